// Round 8
// baseline (228.877 us; speedup 1.0000x reference)
//
#include <hip/hip_runtime.h>

// 2-layer LSTM, B=4096, S=512, F=8, H=10 + FC(10->1) on last step.
// R7: gate-split x layer-split wave specialization -> 4 waves/SIMD.
// Block = 256 thr = 4 waves, 4 elements (16 lanes each, lane=unit j):
//   wave0 = L0-IG: rows {j, 20+j}; ig = sigm(i)*tanh(g) -> igb0 (f32)
//   wave1 = L0-FO: rows {10+j, 30+j}; c0 = sf*c0 + ig; h0 -> h0buf (f16, 2 slots)
//   wave2 = L1-IG: same on [h0_t, h1_{t-1}] -> igb1
//   wave3 = L1-FO: c1/h1 -> h1buf; final FC
// Phase p: L0 computes step p, L1 computes step p-1 (lag 1). Two barriers
// per phase (IG-write->FO-read, FO-write->next-phase reads). 513 phases.
// f16 fdot2 dots (f32 accum), L2E prescaled weights. 1024 blocks x 256.

typedef __fp16 v2h __attribute__((ext_vector_type(2)));

#define L2E 1.4426950408889634f

__device__ __forceinline__ v2h pkh(float a, float b) {
    return __builtin_amdgcn_cvt_pkrtz(a, b);
}

#define SIGM(a)  __builtin_amdgcn_rcpf(1.0f + __builtin_amdgcn_exp2f(-(a)))
#define TANHP(a) fmaf(-2.0f, __builtin_amdgcn_rcpf(1.0f + __builtin_amdgcn_exp2f(a)), 1.0f)
#define DOT2(acc, w, v) (acc) = __builtin_amdgcn_fdot2((w), (v), (acc), false)

__global__ __launch_bounds__(256, 4)
void lstm2_r7(const float* __restrict__ x,
              const float* __restrict__ hid,
              const float* __restrict__ cel,
              const float* __restrict__ Wih0, const float* __restrict__ Whh0,
              const float* __restrict__ bih0, const float* __restrict__ bhh0,
              const float* __restrict__ Wih1, const float* __restrict__ Whh1,
              const float* __restrict__ bih1, const float* __restrict__ bhh1,
              const float* __restrict__ Wfc,  const float* __restrict__ bfc,
              float* __restrict__ out)
{
    __shared__ __fp16 h0buf[2][4][16];   // h0 handoff, 2 slots (parity of p)
    __shared__ __fp16 h1buf[4][16];      // h1 recurrent broadcast
    __shared__ float  igb0[4][16];       // L0 ig handoff
    __shared__ float  igb1[4][16];       // L1 ig handoff

    const int tid  = threadIdx.x;
    const int uwid = __builtin_amdgcn_readfirstlane(tid >> 6);
    const int l16  = tid & 15;
    const int eIB  = (tid & 63) >> 4;    // element in block, 0..3
    const int e    = blockIdx.x * 4 + eIB;
    const int j    = (l16 < 10) ? l16 : 0;
    const bool act = (l16 < 10);

    if (uwid == 0) {
        // ================= L0 IG wave (rows i=j [L2E], g=20+j [2*L2E]) ======
        v2h wxi[4], wxg[4], whi[5], whg[5]; float bi, bg;
        { const int ri = j, rg = 20 + j;
          #pragma unroll
          for (int k = 0; k < 4; ++k) {
              wxi[k] = pkh(Wih0[ri*8+2*k]*L2E,        Wih0[ri*8+2*k+1]*L2E);
              wxg[k] = pkh(Wih0[rg*8+2*k]*(2.0f*L2E), Wih0[rg*8+2*k+1]*(2.0f*L2E));
          }
          #pragma unroll
          for (int k = 0; k < 5; ++k) {
              whi[k] = pkh(Whh0[ri*10+2*k]*L2E,        Whh0[ri*10+2*k+1]*L2E);
              whg[k] = pkh(Whh0[rg*10+2*k]*(2.0f*L2E), Whh0[rg*10+2*k+1]*(2.0f*L2E));
          }
          bi = (bih0[ri] + bhh0[ri]) * L2E;
          bg = (bih0[rg] + bhh0[rg]) * (2.0f*L2E);
        }
        const float4* __restrict__ xp = reinterpret_cast<const float4*>(x + (size_t)e * 4096);
        float4 xa[2], xb[2], xc[2], xd[2];
        xa[0]=xp[0]; xa[1]=xp[1];  xb[0]=xp[2]; xb[1]=xp[3];
        xc[0]=xp[4]; xc[1]=xp[5];  xd[0]=xp[6]; xd[1]=xp[7];
        __syncthreads();   // prologue: h0/h1 init visible

#define PH_L0IG(XB, RS, TN, EN)                                              \
        { if (EN) {                                                          \
            const v2h* hr = (const v2h*)&h0buf[RS][eIB][0];                  \
            v2h h0_=hr[0], h1_=hr[1], h2_=hr[2], h3_=hr[3], h4_=hr[4];       \
            v2h x0_=pkh(XB[0].x,XB[0].y), x1_=pkh(XB[0].z,XB[0].w);          \
            v2h x2_=pkh(XB[1].x,XB[1].y), x3_=pkh(XB[1].z,XB[1].w);          \
            { int tn=(TN)>511?511:(TN); XB[0]=xp[2*tn]; XB[1]=xp[2*tn+1]; }  \
            float ai=bi, ag=bg;                                              \
            DOT2(ai,wxi[0],x0_); DOT2(ag,wxg[0],x0_);                        \
            DOT2(ai,wxi[1],x1_); DOT2(ag,wxg[1],x1_);                        \
            DOT2(ai,wxi[2],x2_); DOT2(ag,wxg[2],x2_);                        \
            DOT2(ai,wxi[3],x3_); DOT2(ag,wxg[3],x3_);                        \
            DOT2(ai,whi[0],h0_); DOT2(ag,whg[0],h0_);                        \
            DOT2(ai,whi[1],h1_); DOT2(ag,whg[1],h1_);                        \
            DOT2(ai,whi[2],h2_); DOT2(ag,whg[2],h2_);                        \
            DOT2(ai,whi[3],h3_); DOT2(ag,whg[3],h3_);                        \
            DOT2(ai,whi[4],h4_); DOT2(ag,whg[4],h4_);                        \
            igb0[eIB][l16] = SIGM(ai) * TANHP(ag);                           \
          }                                                                  \
          __syncthreads(); __syncthreads(); }

        PH_L0IG(xa, 1, 4, true)                       // p = 0
        for (int it = 0; it < 128; ++it) {            // p = 4it+1 .. 4it+4
            PH_L0IG(xb, 0, 4*it+5, true)
            PH_L0IG(xc, 1, 4*it+6, true)
            PH_L0IG(xd, 0, 4*it+7, true)
            PH_L0IG(xa, 1, 4*it+8, (it < 127))        // p=512 skipped
        }
#undef PH_L0IG

    } else if (uwid == 1) {
        // ================= L0 FO wave (rows f=10+j, o=30+j [L2E]) ===========
        v2h wxf[4], wxo[4], whf[5], who[5]; float bf_, bo_;
        { const int rf = 10 + j, ro = 30 + j;
          #pragma unroll
          for (int k = 0; k < 4; ++k) {
              wxf[k] = pkh(Wih0[rf*8+2*k]*L2E, Wih0[rf*8+2*k+1]*L2E);
              wxo[k] = pkh(Wih0[ro*8+2*k]*L2E, Wih0[ro*8+2*k+1]*L2E);
          }
          #pragma unroll
          for (int k = 0; k < 5; ++k) {
              whf[k] = pkh(Whh0[rf*10+2*k]*L2E, Whh0[rf*10+2*k+1]*L2E);
              who[k] = pkh(Whh0[ro*10+2*k]*L2E, Whh0[ro*10+2*k+1]*L2E);
          }
          bf_ = (bih0[rf] + bhh0[rf]) * L2E;
          bo_ = (bih0[ro] + bhh0[ro]) * L2E;
        }
        float cc = cel[e * 10 + j];
        float hj = 0.0f;
        h0buf[1][eIB][l16] = (__fp16)hid[e * 10 + j];   // h0[-1] -> slot 1
        const float4* __restrict__ xp = reinterpret_cast<const float4*>(x + (size_t)e * 4096);
        float4 xa[2], xb[2], xc[2], xd[2];
        xa[0]=xp[0]; xa[1]=xp[1];  xb[0]=xp[2]; xb[1]=xp[3];
        xc[0]=xp[4]; xc[1]=xp[5];  xd[0]=xp[6]; xd[1]=xp[7];
        __syncthreads();

#define PH_L0FO(XB, RS, WS, TN, EN)                                          \
        { float sf_ = 0.0f, so_ = 0.0f;                                      \
          if (EN) {                                                          \
            const v2h* hr = (const v2h*)&h0buf[RS][eIB][0];                  \
            v2h h0_=hr[0], h1_=hr[1], h2_=hr[2], h3_=hr[3], h4_=hr[4];       \
            v2h x0_=pkh(XB[0].x,XB[0].y), x1_=pkh(XB[0].z,XB[0].w);          \
            v2h x2_=pkh(XB[1].x,XB[1].y), x3_=pkh(XB[1].z,XB[1].w);          \
            { int tn=(TN)>511?511:(TN); XB[0]=xp[2*tn]; XB[1]=xp[2*tn+1]; }  \
            float af=bf_, ao=bo_;                                            \
            DOT2(af,wxf[0],x0_); DOT2(ao,wxo[0],x0_);                        \
            DOT2(af,wxf[1],x1_); DOT2(ao,wxo[1],x1_);                        \
            DOT2(af,wxf[2],x2_); DOT2(ao,wxo[2],x2_);                        \
            DOT2(af,wxf[3],x3_); DOT2(ao,wxo[3],x3_);                        \
            DOT2(af,whf[0],h0_); DOT2(ao,who[0],h0_);                        \
            DOT2(af,whf[1],h1_); DOT2(ao,who[1],h1_);                        \
            DOT2(af,whf[2],h2_); DOT2(ao,who[2],h2_);                        \
            DOT2(af,whf[3],h3_); DOT2(ao,who[3],h3_);                        \
            DOT2(af,whf[4],h4_); DOT2(ao,who[4],h4_);                        \
            sf_ = SIGM(af); so_ = SIGM(ao);                                  \
          }                                                                  \
          __syncthreads();                                                   \
          if (EN) {                                                          \
            float ig = igb0[eIB][l16];                                       \
            cc = fmaf(sf_, cc, ig);                                          \
            hj = so_ * TANHP((2.0f*L2E) * cc);                               \
            h0buf[WS][eIB][l16] = (__fp16)hj;                                \
          }                                                                  \
          __syncthreads(); }

        PH_L0FO(xa, 1, 0, 4, true)                    // p = 0
        for (int it = 0; it < 128; ++it) {
            PH_L0FO(xb, 0, 1, 4*it+5, true)
            PH_L0FO(xc, 1, 0, 4*it+6, true)
            PH_L0FO(xd, 0, 1, 4*it+7, true)
            PH_L0FO(xa, 1, 0, 4*it+8, (it < 127))
        }
#undef PH_L0FO

        if (act) {
            out[4096          + e * 10 + l16] = hj;   // h0_T
            out[4096 + 81920  + e * 10 + l16] = cc;   // c0_T
        }

    } else if (uwid == 2) {
        // ================= L1 IG wave (rows i=j [L2E], g=20+j [2*L2E]) ======
        v2h wii[5], wig[5], wri[5], wrg[5]; float bi, bg;
        { const int ri = j, rg = 20 + j;
          #pragma unroll
          for (int k = 0; k < 5; ++k) {
              wii[k] = pkh(Wih1[ri*10+2*k]*L2E,        Wih1[ri*10+2*k+1]*L2E);
              wig[k] = pkh(Wih1[rg*10+2*k]*(2.0f*L2E), Wih1[rg*10+2*k+1]*(2.0f*L2E));
              wri[k] = pkh(Whh1[ri*10+2*k]*L2E,        Whh1[ri*10+2*k+1]*L2E);
              wrg[k] = pkh(Whh1[rg*10+2*k]*(2.0f*L2E), Whh1[rg*10+2*k+1]*(2.0f*L2E));
          }
          bi = (bih1[ri] + bhh1[ri]) * L2E;
          bg = (bih1[rg] + bhh1[rg]) * (2.0f*L2E);
        }
        __syncthreads();

#define PH_L1IG(RS, EN)                                                      \
        { if (EN) {                                                          \
            const v2h* hin = (const v2h*)&h0buf[RS][eIB][0];                 \
            const v2h* hr  = (const v2h*)&h1buf[eIB][0];                     \
            v2h p0=hin[0], p1=hin[1], p2=hin[2], p3=hin[3], p4=hin[4];       \
            v2h q0=hr[0],  q1=hr[1],  q2=hr[2],  q3=hr[3],  q4=hr[4];        \
            float ai=bi, ag=bg;                                              \
            DOT2(ai,wii[0],p0); DOT2(ag,wig[0],p0);                          \
            DOT2(ai,wii[1],p1); DOT2(ag,wig[1],p1);                          \
            DOT2(ai,wii[2],p2); DOT2(ag,wig[2],p2);                          \
            DOT2(ai,wii[3],p3); DOT2(ag,wig[3],p3);                          \
            DOT2(ai,wii[4],p4); DOT2(ag,wig[4],p4);                          \
            DOT2(ai,wri[0],q0); DOT2(ag,wrg[0],q0);                          \
            DOT2(ai,wri[1],q1); DOT2(ag,wrg[1],q1);                          \
            DOT2(ai,wri[2],q2); DOT2(ag,wrg[2],q2);                          \
            DOT2(ai,wri[3],q3); DOT2(ag,wrg[3],q3);                          \
            DOT2(ai,wri[4],q4); DOT2(ag,wrg[4],q4);                          \
            igb1[eIB][l16] = SIGM(ai) * TANHP(ag);                           \
          }                                                                  \
          __syncthreads(); __syncthreads(); }

        PH_L1IG(1, false)                              // p = 0 (idle)
        for (int it = 0; it < 128; ++it) {
            PH_L1IG(0, true)
            PH_L1IG(1, true)
            PH_L1IG(0, true)
            PH_L1IG(1, true)
        }
#undef PH_L1IG

    } else {
        // ================= L1 FO wave (rows f=10+j, o=30+j [L2E]) ===========
        v2h wif[5], wio[5], wrf[5], wro[5]; float bf_, bo_;
        { const int rf = 10 + j, ro = 30 + j;
          #pragma unroll
          for (int k = 0; k < 5; ++k) {
              wif[k] = pkh(Wih1[rf*10+2*k]*L2E, Wih1[rf*10+2*k+1]*L2E);
              wio[k] = pkh(Wih1[ro*10+2*k]*L2E, Wih1[ro*10+2*k+1]*L2E);
              wrf[k] = pkh(Whh1[rf*10+2*k]*L2E, Whh1[rf*10+2*k+1]*L2E);
              wro[k] = pkh(Whh1[ro*10+2*k]*L2E, Whh1[ro*10+2*k+1]*L2E);
          }
          bf_ = (bih1[rf] + bhh1[rf]) * L2E;
          bo_ = (bih1[ro] + bhh1[ro]) * L2E;
        }
        const float wfc = act ? Wfc[j] : 0.0f;
        float cc = cel[40960 + e * 10 + j];
        float hj = 0.0f;
        h1buf[eIB][l16] = (__fp16)hid[40960 + e * 10 + j];   // h1[-1]
        __syncthreads();

#define PH_L1FO(RS, EN)                                                      \
        { float sf_ = 0.0f, so_ = 0.0f;                                      \
          if (EN) {                                                          \
            const v2h* hin = (const v2h*)&h0buf[RS][eIB][0];                 \
            const v2h* hr  = (const v2h*)&h1buf[eIB][0];                     \
            v2h p0=hin[0], p1=hin[1], p2=hin[2], p3=hin[3], p4=hin[4];       \
            v2h q0=hr[0],  q1=hr[1],  q2=hr[2],  q3=hr[3],  q4=hr[4];        \
            float af=bf_, ao=bo_;                                            \
            DOT2(af,wif[0],p0); DOT2(ao,wio[0],p0);                          \
            DOT2(af,wif[1],p1); DOT2(ao,wio[1],p1);                          \
            DOT2(af,wif[2],p2); DOT2(ao,wio[2],p2);                          \
            DOT2(af,wif[3],p3); DOT2(ao,wio[3],p3);                          \
            DOT2(af,wif[4],p4); DOT2(ao,wio[4],p4);                          \
            DOT2(af,wrf[0],q0); DOT2(ao,wro[0],q0);                          \
            DOT2(af,wrf[1],q1); DOT2(ao,wro[1],q1);                          \
            DOT2(af,wrf[2],q2); DOT2(ao,wro[2],q2);                          \
            DOT2(af,wrf[3],q3); DOT2(ao,wro[3],q3);                          \
            DOT2(af,wrf[4],q4); DOT2(ao,wro[4],q4);                          \
            sf_ = SIGM(af); so_ = SIGM(ao);                                  \
          }                                                                  \
          __syncthreads();                                                   \
          if (EN) {                                                          \
            float ig = igb1[eIB][l16];                                       \
            cc = fmaf(sf_, cc, ig);                                          \
            hj = so_ * TANHP((2.0f*L2E) * cc);                               \
            h1buf[eIB][l16] = (__fp16)hj;                                    \
          }                                                                  \
          __syncthreads(); }

        PH_L1FO(1, false)                              // p = 0 (idle)
        for (int it = 0; it < 128; ++it) {
            PH_L1FO(0, true)
            PH_L1FO(1, true)
            PH_L1FO(0, true)
            PH_L1FO(1, true)
        }
#undef PH_L1FO

        float p = hj * wfc;
        #pragma unroll
        for (int off = 8; off > 0; off >>= 1) p += __shfl_xor(p, off, 16);
        if (l16 == 0) out[e] = p + bfc[0];
        if (act) {
            out[4096 + 40960  + e * 10 + l16] = hj;   // h1_T
            out[4096 + 122880 + e * 10 + l16] = cc;   // c1_T
        }
    }
}

extern "C" void kernel_launch(void* const* d_in, const int* in_sizes, int n_in,
                              void* d_out, int out_size, void* d_ws, size_t ws_size,
                              hipStream_t stream) {
    const float* x    = (const float*)d_in[0];
    const float* hid  = (const float*)d_in[1];
    const float* cel  = (const float*)d_in[2];
    const float* Wih0 = (const float*)d_in[3];
    const float* Whh0 = (const float*)d_in[4];
    const float* bih0 = (const float*)d_in[5];
    const float* bhh0 = (const float*)d_in[6];
    const float* Wih1 = (const float*)d_in[7];
    const float* Whh1 = (const float*)d_in[8];
    const float* bih1 = (const float*)d_in[9];
    const float* bhh1 = (const float*)d_in[10];
    const float* Wfc  = (const float*)d_in[11];
    const float* bfc  = (const float*)d_in[12];

    hipLaunchKernelGGL(lstm2_r7, dim3(1024), dim3(256), 0, stream,
                       x, hid, cel, Wih0, Whh0, bih0, bhh0,
                       Wih1, Whh1, bih1, bhh1, Wfc, bfc,
                       (float*)d_out);
}

// Round 9
// 173.283 us; speedup vs baseline: 1.3208x; 1.3208x over previous
//
#include <hip/hip_runtime.h>

// 2-layer LSTM, B=4096, S=512, F=8, H=10 + FC(10->1) on last step.
// R8: 20-lane element groups, 2 gate-rows per lane (94% lane use).
//  lane l20<10: rows (i=l20, g=20+l20); lane l20>=10: rows (f=l20, o=20+l20)
//  -> rowA=l20, rowB=20+l20 uniformly. Unified activation act=a*rcp(1+exp2(-z))+b
//  (sigma: a=1,b=0; tanh: a=2,b=-1) -> one instruction stream, 6 trans/step/3elem.
//  ig=act1*act2 lane-local; (sf,so) via 2x ds_bpermute (f32) from lane+10.
//  3 elements per wave; h broadcast via 20-half LDS rows (pad lanes land in
//  read-dead half). R6's L0/L1 producer-consumer schedule kept verbatim
//  (8 slots, barrier per 4 steps, 128 barriers). 683 blocks x 256 thr.

typedef __fp16 v2h __attribute__((ext_vector_type(2)));

#define L2E 1.4426950408889634f

__device__ __forceinline__ v2h pkh(float a, float b) {
    return __builtin_amdgcn_cvt_pkrtz(a, b);
}
__device__ __forceinline__ float bpermf(int baddr, float v) {
    int r = __builtin_amdgcn_ds_bpermute(baddr, __builtin_bit_cast(int, v));
    return __builtin_bit_cast(float, r);
}

#define SIGM(a)  __builtin_amdgcn_rcpf(1.0f + __builtin_amdgcn_exp2f(-(a)))
#define TANHP(a) fmaf(-2.0f, __builtin_amdgcn_rcpf(1.0f + __builtin_amdgcn_exp2f(a)), 1.0f)
#define DOT2(acc, w, v) (acc) = __builtin_amdgcn_fdot2((w), (v), (acc), false)

__global__ __launch_bounds__(256, 2)
void lstm2_r8(const float* __restrict__ x,
              const float* __restrict__ hid,
              const float* __restrict__ cel,
              const float* __restrict__ Wih0, const float* __restrict__ Whh0,
              const float* __restrict__ bih0, const float* __restrict__ bhh0,
              const float* __restrict__ Wih1, const float* __restrict__ Whh1,
              const float* __restrict__ bih1, const float* __restrict__ bhh1,
              const float* __restrict__ Wfc,  const float* __restrict__ bfc,
              float* __restrict__ out)
{
    __shared__ __fp16 h0buf[8][6][20];   // 8 slots x 6 elems x 20-half rows
    __shared__ __fp16 h1buf[6][20];      // L1 self-broadcast
    __shared__ float  fcb[6][10];        // FC partials

    const int tid  = threadIdx.x;
    const int lane = tid & 63;
    const int wid  = tid >> 6;
    const int uwid = __builtin_amdgcn_readfirstlane(wid);
    int grp = lane / 20;
    int l20 = lane - grp * 20;
    if (lane >= 60) { grp = 2; l20 = 19; }   // pad lanes duplicate lane 59
    const int  ju       = (l20 < 10) ? l20 : l20 - 10;  // unit index
    const bool unitlane = (l20 < 10);
    const int  eIw = (wid & 1) * 3 + grp;    // element in block, 0..5
    const int  e   = blockIdx.x * 6 + eIw;
    const int  ec  = (e < 4095) ? e : 4095;  // clamped for loads
    const int  baddr = ((l20 < 10) ? (lane + 10) : lane) * 4;  // bpermute src

    const float alpha2 = unitlane ? 2.0f : 1.0f;   // rowB act: tanh vs sigma
    const float beta2  = unitlane ? -1.0f : 0.0f;
    const float scB    = unitlane ? 2.0f * L2E : L2E;
    const int   rA = l20, rB = 20 + l20;

    if (uwid < 2) {
        // ================= LAYER-0 (producer) waves =================
        v2h wxA[4], wxB[4], whA[5], whB[5];
        #pragma unroll
        for (int k = 0; k < 4; ++k) {
            wxA[k] = pkh(Wih0[rA*8+2*k]*L2E, Wih0[rA*8+2*k+1]*L2E);
            wxB[k] = pkh(Wih0[rB*8+2*k]*scB, Wih0[rB*8+2*k+1]*scB);
        }
        #pragma unroll
        for (int k = 0; k < 5; ++k) {
            whA[k] = pkh(Whh0[rA*10+2*k]*L2E, Whh0[rA*10+2*k+1]*L2E);
            whB[k] = pkh(Whh0[rB*10+2*k]*scB, Whh0[rB*10+2*k+1]*scB);
        }
        const float bA = (bih0[rA] + bhh0[rA]) * L2E;
        const float bB = (bih0[rB] + bhh0[rB]) * scB;

        v2h hv[5];
        #pragma unroll
        for (int k = 0; k < 5; ++k) hv[k] = pkh(hid[ec*10+2*k], hid[ec*10+2*k+1]);
        float cc = cel[ec * 10 + ju];
        float hj = 0.0f;

        __fp16* const wbase = &h0buf[0][eIw][0];   // slot stride 120 halves
        __fp16* const wlane = wbase + l20;

        const float4* __restrict__ xp = reinterpret_cast<const float4*>(x + (size_t)ec * 4096);
        float4 xb0[2], xb1[2], xb2[2], xb3[2];
        xb0[0]=xp[0]; xb0[1]=xp[1];  xb1[0]=xp[2]; xb1[1]=xp[3];
        xb2[0]=xp[4]; xb2[1]=xp[5];  xb3[0]=xp[6]; xb3[1]=xp[7];

#define L0STEP(XB, S, TN)                                                    \
        {                                                                    \
            v2h x0=pkh(XB[0].x,XB[0].y), x1=pkh(XB[0].z,XB[0].w);            \
            v2h x2=pkh(XB[1].x,XB[1].y), x3=pkh(XB[1].z,XB[1].w);            \
            { int tn=(TN)>511?511:(TN); XB[0]=xp[2*tn]; XB[1]=xp[2*tn+1]; }  \
            float aA = bA, aB = bB;                                          \
            DOT2(aA,wxA[0],x0); DOT2(aB,wxB[0],x0);                          \
            DOT2(aA,wxA[1],x1); DOT2(aB,wxB[1],x1);                          \
            DOT2(aA,wxA[2],x2); DOT2(aB,wxB[2],x2);                          \
            DOT2(aA,wxA[3],x3); DOT2(aB,wxB[3],x3);                          \
            DOT2(aA,whA[0],hv[0]); DOT2(aB,whB[0],hv[0]);                    \
            DOT2(aA,whA[1],hv[1]); DOT2(aB,whB[1],hv[1]);                    \
            DOT2(aA,whA[2],hv[2]); DOT2(aB,whB[2],hv[2]);                    \
            DOT2(aA,whA[3],hv[3]); DOT2(aB,whB[3],hv[3]);                    \
            DOT2(aA,whA[4],hv[4]); DOT2(aB,whB[4],hv[4]);                    \
            float r1 = SIGM(aA);                                             \
            float r2 = __builtin_amdgcn_rcpf(1.0f + __builtin_amdgcn_exp2f(-aB)); \
            float act2 = fmaf(alpha2, r2, beta2);                            \
            float ig = r1 * act2;                                            \
            float sf = bpermf(baddr, r1);                                    \
            float so = bpermf(baddr, act2);                                  \
            cc = fmaf(sf, cc, ig);                                           \
            hj = so * TANHP((2.0f*L2E) * cc);                                \
            wlane[(S)*120] = (__fp16)hj;                                     \
            { const v2h* rb = (const v2h*)(wbase + (S)*120);                 \
              hv[0]=rb[0]; hv[1]=rb[1]; hv[2]=rb[2]; hv[3]=rb[3]; hv[4]=rb[4]; } \
        }

        for (int it = 0; it < 64; ++it) {
            const int tb = 8 * it;
            L0STEP(xb0, 0, tb + 4)
            L0STEP(xb1, 1, tb + 5)
            L0STEP(xb2, 2, tb + 6)
            L0STEP(xb3, 3, tb + 7)
            __syncthreads();
            L0STEP(xb0, 4, tb + 8)
            L0STEP(xb1, 5, tb + 9)
            L0STEP(xb2, 6, tb + 10)
            L0STEP(xb3, 7, tb + 11)
            __syncthreads();
        }
#undef L0STEP

        __syncthreads();   // match L1's epilogue barrier
        if (unitlane && e < 4096) {
            out[4096          + e * 10 + ju] = hj;   // h0_T
            out[4096 + 81920  + e * 10 + ju] = cc;   // c0_T
        }

    } else {
        // ================= LAYER-1 (consumer) waves =================
        v2h wiA[5], wiB[5], whA[5], whB[5];
        #pragma unroll
        for (int k = 0; k < 5; ++k) {
            wiA[k] = pkh(Wih1[rA*10+2*k]*L2E, Wih1[rA*10+2*k+1]*L2E);
            wiB[k] = pkh(Wih1[rB*10+2*k]*scB, Wih1[rB*10+2*k+1]*scB);
            whA[k] = pkh(Whh1[rA*10+2*k]*L2E, Whh1[rA*10+2*k+1]*L2E);
            whB[k] = pkh(Whh1[rB*10+2*k]*scB, Whh1[rB*10+2*k+1]*scB);
        }
        const float bA = (bih1[rA] + bhh1[rA]) * L2E;
        const float bB = (bih1[rB] + bhh1[rB]) * scB;
        const float wfc = Wfc[ju];

        v2h hv[5];
        #pragma unroll
        for (int k = 0; k < 5; ++k) hv[k] = pkh(hid[40960+ec*10+2*k], hid[40960+ec*10+2*k+1]);
        float cc = cel[40960 + ec * 10 + ju];
        float hj = 0.0f;

        const __fp16* const rbase = &h0buf[0][eIw][0];   // slot stride 120 halves
        __fp16* const h1w  = &h1buf[eIw][0];
        __fp16* const h1wl = h1w + l20;

#define L1STEP(SR)                                                           \
        {                                                                    \
            const v2h* ir = (const v2h*)(rbase + (SR)*120);                  \
            v2h p0=ir[0], p1=ir[1], p2=ir[2], p3=ir[3], p4=ir[4];            \
            float aA = bA, aB = bB;                                          \
            DOT2(aA,wiA[0],p0); DOT2(aB,wiB[0],p0);                          \
            DOT2(aA,wiA[1],p1); DOT2(aB,wiB[1],p1);                          \
            DOT2(aA,wiA[2],p2); DOT2(aB,wiB[2],p2);                          \
            DOT2(aA,wiA[3],p3); DOT2(aB,wiB[3],p3);                          \
            DOT2(aA,wiA[4],p4); DOT2(aB,wiB[4],p4);                          \
            DOT2(aA,whA[0],hv[0]); DOT2(aB,whB[0],hv[0]);                    \
            DOT2(aA,whA[1],hv[1]); DOT2(aB,whB[1],hv[1]);                    \
            DOT2(aA,whA[2],hv[2]); DOT2(aB,whB[2],hv[2]);                    \
            DOT2(aA,whA[3],hv[3]); DOT2(aB,whB[3],hv[3]);                    \
            DOT2(aA,whA[4],hv[4]); DOT2(aB,whB[4],hv[4]);                    \
            float r1 = SIGM(aA);                                             \
            float r2 = __builtin_amdgcn_rcpf(1.0f + __builtin_amdgcn_exp2f(-aB)); \
            float act2 = fmaf(alpha2, r2, beta2);                            \
            float ig = r1 * act2;                                            \
            float sf = bpermf(baddr, r1);                                    \
            float so = bpermf(baddr, act2);                                  \
            cc = fmaf(sf, cc, ig);                                           \
            hj = so * TANHP((2.0f*L2E) * cc);                                \
            h1wl[0] = (__fp16)hj;                                            \
            { const v2h* rb = (const v2h*)h1w;                               \
              hv[0]=rb[0]; hv[1]=rb[1]; hv[2]=rb[2]; hv[3]=rb[3]; hv[4]=rb[4]; } \
        }

        for (int it = 0; it < 64; ++it) {
            __syncthreads();
            L1STEP(0)
            L1STEP(1)
            L1STEP(2)
            L1STEP(3)
            __syncthreads();
            L1STEP(4)
            L1STEP(5)
            L1STEP(6)
            L1STEP(7)
        }
#undef L1STEP

        if (unitlane) fcb[eIw][ju] = hj * wfc;
        __syncthreads();
        if (l20 == 0 && e < 4096) {
            float p = bfc[0];
            #pragma unroll
            for (int k = 0; k < 10; ++k) p += fcb[eIw][k];
            out[e] = p;
        }
        if (unitlane && e < 4096) {
            out[4096 + 40960  + e * 10 + ju] = hj;   // h1_T
            out[4096 + 122880 + e * 10 + ju] = cc;   // c1_T
        }
    }
}

extern "C" void kernel_launch(void* const* d_in, const int* in_sizes, int n_in,
                              void* d_out, int out_size, void* d_ws, size_t ws_size,
                              hipStream_t stream) {
    const float* x    = (const float*)d_in[0];
    const float* hid  = (const float*)d_in[1];
    const float* cel  = (const float*)d_in[2];
    const float* Wih0 = (const float*)d_in[3];
    const float* Whh0 = (const float*)d_in[4];
    const float* bih0 = (const float*)d_in[5];
    const float* bhh0 = (const float*)d_in[6];
    const float* Wih1 = (const float*)d_in[7];
    const float* Whh1 = (const float*)d_in[8];
    const float* bih1 = (const float*)d_in[9];
    const float* bhh1 = (const float*)d_in[10];
    const float* Wfc  = (const float*)d_in[11];
    const float* bfc  = (const float*)d_in[12];

    // 683 blocks x 6 elements = 4098 slots (2 padded, store-masked)
    hipLaunchKernelGGL(lstm2_r8, dim3(683), dim3(256), 0, stream,
                       x, hid, cel, Wih0, Whh0, bih0, bhh0,
                       Wih1, Whh1, bih1, bhh1, Wfc, bfc,
                       (float*)d_out);
}

// Round 11
// 160.499 us; speedup vs baseline: 1.4260x; 1.0796x over previous
//
#include <hip/hip_runtime.h>

// 2-layer LSTM, B=4096, S=512, F=8, H=10 + FC(10->1) on last step.
// R10: R9 with the NaN fixed. Root cause: h readback via int4/int punned
// loads after an __fp16 store -> TBAA says no alias -> compiler reorders
// ds_read_b128 before ds_write_b16 (R8's v2h loads kept ordering). Fix:
// packed readback as v8h (__fp16 x8) + v2h, bit_cast to v2h pieces — same
// TBAA class as the store; LDS arrays aligned(16) for b128.
// Structure (from R9): 20-lane element groups (2 gate-rows/lane, 94% lane
// use), 3 elems/wave; producer(L0)/consumer(L1) wave pairs; distance-1
// x-dot software pipeline (h-chain = 5 serial dots); 16 h0 slots, barrier
// every 8 steps (64 barriers). 683 blocks x 256 thr.

typedef __fp16 v2h __attribute__((ext_vector_type(2)));
typedef __fp16 v8h __attribute__((ext_vector_type(8)));
struct h4 { v2h a, b, c, d; };

#define L2E 1.4426950408889634f

__device__ __forceinline__ v2h pkh(float a, float b) {
    return __builtin_amdgcn_cvt_pkrtz(a, b);
}
__device__ __forceinline__ float bpermf(int baddr, float v) {
    int r = __builtin_amdgcn_ds_bpermute(baddr, __builtin_bit_cast(int, v));
    return __builtin_bit_cast(float, r);
}

#define SIGM(a)  __builtin_amdgcn_rcpf(1.0f + __builtin_amdgcn_exp2f(-(a)))
#define TANHP(a) fmaf(-2.0f, __builtin_amdgcn_rcpf(1.0f + __builtin_amdgcn_exp2f(a)), 1.0f)
#define DOT2(acc, w, v) (acc) = __builtin_amdgcn_fdot2((w), (v), (acc), false)

__global__ __launch_bounds__(256, 2)
void lstm2_r10(const float* __restrict__ x,
               const float* __restrict__ hid,
               const float* __restrict__ cel,
               const float* __restrict__ Wih0, const float* __restrict__ Whh0,
               const float* __restrict__ bih0, const float* __restrict__ bhh0,
               const float* __restrict__ Wih1, const float* __restrict__ Whh1,
               const float* __restrict__ bih1, const float* __restrict__ bhh1,
               const float* __restrict__ Wfc,  const float* __restrict__ bfc,
               float* __restrict__ out)
{
    __shared__ __attribute__((aligned(16))) __fp16 h0buf[16][6][24]; // 4.6KB
    __shared__ __attribute__((aligned(16))) __fp16 h1buf[6][24];
    __shared__ float fcb[6][10];

    const int tid  = threadIdx.x;
    const int lane = tid & 63;
    const int wid  = tid >> 6;
    const int uwid = __builtin_amdgcn_readfirstlane(wid);
    int grp = lane / 20;
    int l20 = lane - grp * 20;
    if (lane >= 60) { grp = 2; l20 = 19; }   // pad lanes duplicate lane 59
    const int  ju       = (l20 < 10) ? l20 : l20 - 10;  // unit index
    const bool unitlane = (l20 < 10);
    const int  eIw = (wid & 1) * 3 + grp;    // element in block, 0..5
    const int  e   = blockIdx.x * 6 + eIw;
    const int  ec  = (e < 4095) ? e : 4095;  // clamped for loads
    const int  baddr = ((l20 < 10) ? (lane + 10) : lane) * 4;  // bpermute src

    const float alpha2 = unitlane ? 2.0f : 1.0f;   // rowB act: tanh vs sigma
    const float beta2  = unitlane ? -1.0f : 0.0f;
    const float scB    = unitlane ? 2.0f * L2E : L2E;
    const int   rA = l20, rB = 20 + l20;

// TBAA-safe packed row read: PTR is __fp16*, 16B-aligned
#define READROW(PTR, H)                                                      \
    { v8h w0_ = *(const v8h*)(PTR);                                          \
      v2h w1_ = *(const v2h*)((PTR) + 8);                                    \
      h4 q_ = __builtin_bit_cast(h4, w0_);                                   \
      H[0]=q_.a; H[1]=q_.b; H[2]=q_.c; H[3]=q_.d; H[4]=w1_; }

    if (uwid < 2) {
        // ================= LAYER-0 (producer) waves =================
        v2h wxA[4], wxB[4], whA[5], whB[5];
        #pragma unroll
        for (int k = 0; k < 4; ++k) {
            wxA[k] = pkh(Wih0[rA*8+2*k]*L2E, Wih0[rA*8+2*k+1]*L2E);
            wxB[k] = pkh(Wih0[rB*8+2*k]*scB, Wih0[rB*8+2*k+1]*scB);
        }
        #pragma unroll
        for (int k = 0; k < 5; ++k) {
            whA[k] = pkh(Whh0[rA*10+2*k]*L2E, Whh0[rA*10+2*k+1]*L2E);
            whB[k] = pkh(Whh0[rB*10+2*k]*scB, Whh0[rB*10+2*k+1]*scB);
        }
        const float bA = (bih0[rA] + bhh0[rA]) * L2E;
        const float bB = (bih0[rB] + bhh0[rB]) * scB;

        v2h hv[5];
        #pragma unroll
        for (int k = 0; k < 5; ++k) hv[k] = pkh(hid[ec*10+2*k], hid[ec*10+2*k+1]);
        float cc = cel[ec * 10 + ju];
        float hj = 0.0f;

        __fp16* const wbase = &h0buf[0][eIw][0];   // slot stride 144 halves
        __fp16* const wlane = wbase + l20;

        const float4* __restrict__ xp = reinterpret_cast<const float4*>(x + (size_t)ec * 4096);
        float4 xb0[2], xb1[2], xb2[2], xb3[2];
        xb0[0]=xp[0]; xb0[1]=xp[1];  xb1[0]=xp[2]; xb1[1]=xp[3];
        xb2[0]=xp[4]; xb2[1]=xp[5];  xb3[0]=xp[6]; xb3[1]=xp[7];

        float axA[2], axB[2];
        // prologue: ax(step 0) from xb0, then refill xb0 <- step 4
        {
            v2h x0=pkh(xb0[0].x,xb0[0].y), x1=pkh(xb0[0].z,xb0[0].w);
            v2h x2=pkh(xb0[1].x,xb0[1].y), x3=pkh(xb0[1].z,xb0[1].w);
            xb0[0]=xp[8]; xb0[1]=xp[9];
            float nA=bA, nB=bB;
            DOT2(nA,wxA[0],x0); DOT2(nB,wxB[0],x0);
            DOT2(nA,wxA[1],x1); DOT2(nB,wxB[1],x1);
            DOT2(nA,wxA[2],x2); DOT2(nB,wxB[2],x2);
            DOT2(nA,wxA[3],x3); DOT2(nB,wxB[3],x3);
            axA[0]=nA; axB[0]=nB;
        }

// L0 step s: filler = ax(s+1) from XB + refill XB; current uses ax[PC];
// write h slot S; packed TBAA-safe readback.
#define L0STEP(S, XB, TN, PC, PN)                                            \
        {                                                                    \
            v2h x0=pkh(XB[0].x,XB[0].y), x1=pkh(XB[0].z,XB[0].w);            \
            v2h x2=pkh(XB[1].x,XB[1].y), x3=pkh(XB[1].z,XB[1].w);            \
            { int tn=(TN)>511?511:(TN); XB[0]=xp[2*tn]; XB[1]=xp[2*tn+1]; }  \
            float nA=bA, nB=bB;                                              \
            DOT2(nA,wxA[0],x0); DOT2(nB,wxB[0],x0);                          \
            DOT2(nA,wxA[1],x1); DOT2(nB,wxB[1],x1);                          \
            DOT2(nA,wxA[2],x2); DOT2(nB,wxB[2],x2);                          \
            DOT2(nA,wxA[3],x3); DOT2(nB,wxB[3],x3);                          \
            axA[PN]=nA; axB[PN]=nB;                                          \
            float aA=axA[PC], aB=axB[PC];                                    \
            DOT2(aA,whA[0],hv[0]); DOT2(aB,whB[0],hv[0]);                    \
            DOT2(aA,whA[1],hv[1]); DOT2(aB,whB[1],hv[1]);                    \
            DOT2(aA,whA[2],hv[2]); DOT2(aB,whB[2],hv[2]);                    \
            DOT2(aA,whA[3],hv[3]); DOT2(aB,whB[3],hv[3]);                    \
            DOT2(aA,whA[4],hv[4]); DOT2(aB,whB[4],hv[4]);                    \
            float r1 = SIGM(aA);                                             \
            float r2 = __builtin_amdgcn_rcpf(1.0f + __builtin_amdgcn_exp2f(-aB)); \
            float act2 = fmaf(alpha2, r2, beta2);                            \
            float ig = r1 * act2;                                            \
            float sf = bpermf(baddr, r1);                                    \
            float so = bpermf(baddr, act2);                                  \
            cc = fmaf(sf, cc, ig);                                           \
            hj = so * TANHP((2.0f*L2E) * cc);                                \
            wlane[(S)*144] = (__fp16)hj;                                     \
            READROW(wbase + (S)*144, hv)                                     \
        }

        for (int it = 0; it < 32; ++it) {
            const int tb = 16 * it;
            L0STEP(0,  xb1, tb+5,  0, 1)
            L0STEP(1,  xb2, tb+6,  1, 0)
            L0STEP(2,  xb3, tb+7,  0, 1)
            L0STEP(3,  xb0, tb+8,  1, 0)
            L0STEP(4,  xb1, tb+9,  0, 1)
            L0STEP(5,  xb2, tb+10, 1, 0)
            L0STEP(6,  xb3, tb+11, 0, 1)
            L0STEP(7,  xb0, tb+12, 1, 0)
            __syncthreads();
            L0STEP(8,  xb1, tb+13, 0, 1)
            L0STEP(9,  xb2, tb+14, 1, 0)
            L0STEP(10, xb3, tb+15, 0, 1)
            L0STEP(11, xb0, tb+16, 1, 0)
            L0STEP(12, xb1, tb+17, 0, 1)
            L0STEP(13, xb2, tb+18, 1, 0)
            L0STEP(14, xb3, tb+19, 0, 1)
            L0STEP(15, xb0, tb+20, 1, 0)
            __syncthreads();
        }
#undef L0STEP

        __syncthreads();   // pair with L1's FC epilogue barrier
        if (unitlane && e < 4096) {
            out[4096          + e * 10 + ju] = hj;   // h0_T
            out[4096 + 81920  + e * 10 + ju] = cc;   // c0_T
        }

    } else {
        // ================= LAYER-1 (consumer) waves =================
        v2h wiA[5], wiB[5], whA[5], whB[5];
        #pragma unroll
        for (int k = 0; k < 5; ++k) {
            wiA[k] = pkh(Wih1[rA*10+2*k]*L2E, Wih1[rA*10+2*k+1]*L2E);
            wiB[k] = pkh(Wih1[rB*10+2*k]*scB, Wih1[rB*10+2*k+1]*scB);
            whA[k] = pkh(Whh1[rA*10+2*k]*L2E, Whh1[rA*10+2*k+1]*L2E);
            whB[k] = pkh(Whh1[rB*10+2*k]*scB, Whh1[rB*10+2*k+1]*scB);
        }
        const float bA = (bih1[rA] + bhh1[rA]) * L2E;
        const float bB = (bih1[rB] + bhh1[rB]) * scB;
        const float wfc = Wfc[ju];

        v2h hv[5];
        #pragma unroll
        for (int k = 0; k < 5; ++k) hv[k] = pkh(hid[40960+ec*10+2*k], hid[40960+ec*10+2*k+1]);
        float cc = cel[40960 + ec * 10 + ju];
        float hj = 0.0f;

        const __fp16* const rbase = &h0buf[0][eIw][0];   // slot stride 144 halves
        __fp16* const h1w  = &h1buf[eIw][0];
        __fp16* const h1wl = h1w + l20;

        float axA[2], axB[2];

// input-dots (bias + 5 dots x2) for slot S -> ax parity P
#define L1PRE(S, P)                                                          \
        {                                                                    \
            v2h pr[5];                                                       \
            READROW(rbase + (S)*144, pr)                                     \
            float nA=bA, nB=bB;                                              \
            DOT2(nA,wiA[0],pr[0]); DOT2(nB,wiB[0],pr[0]);                    \
            DOT2(nA,wiA[1],pr[1]); DOT2(nB,wiB[1],pr[1]);                    \
            DOT2(nA,wiA[2],pr[2]); DOT2(nB,wiB[2],pr[2]);                    \
            DOT2(nA,wiA[3],pr[3]); DOT2(nB,wiB[3],pr[3]);                    \
            DOT2(nA,wiA[4],pr[4]); DOT2(nB,wiB[4],pr[4]);                    \
            axA[P]=nA; axB[P]=nB;                                            \
        }

// current step using ax parity PC: h-dots, acts, c/h, h1 write+readback
#define L1CORE(PC)                                                           \
        {                                                                    \
            float aA=axA[PC], aB=axB[PC];                                    \
            DOT2(aA,whA[0],hv[0]); DOT2(aB,whB[0],hv[0]);                    \
            DOT2(aA,whA[1],hv[1]); DOT2(aB,whB[1],hv[1]);                    \
            DOT2(aA,whA[2],hv[2]); DOT2(aB,whB[2],hv[2]);                    \
            DOT2(aA,whA[3],hv[3]); DOT2(aB,whB[3],hv[3]);                    \
            DOT2(aA,whA[4],hv[4]); DOT2(aB,whB[4],hv[4]);                    \
            float r1 = SIGM(aA);                                             \
            float r2 = __builtin_amdgcn_rcpf(1.0f + __builtin_amdgcn_exp2f(-aB)); \
            float act2 = fmaf(alpha2, r2, beta2);                            \
            float ig = r1 * act2;                                            \
            float sf = bpermf(baddr, r1);                                    \
            float so = bpermf(baddr, act2);                                  \
            cc = fmaf(sf, cc, ig);                                           \
            hj = so * TANHP((2.0f*L2E) * cc);                                \
            h1wl[0] = (__fp16)hj;                                            \
            READROW(h1w, hv)                                                 \
        }

        for (int it = 0; it < 32; ++it) {
            __syncthreads();
            L1PRE(0, 0)
            L1PRE(1, 1) L1CORE(0)
            L1PRE(2, 0) L1CORE(1)
            L1PRE(3, 1) L1CORE(0)
            L1PRE(4, 0) L1CORE(1)
            L1PRE(5, 1) L1CORE(0)
            L1PRE(6, 0) L1CORE(1)
            L1PRE(7, 1) L1CORE(0)
            L1CORE(1)
            __syncthreads();
            L1PRE(8, 0)
            L1PRE(9,  1) L1CORE(0)
            L1PRE(10, 0) L1CORE(1)
            L1PRE(11, 1) L1CORE(0)
            L1PRE(12, 0) L1CORE(1)
            L1PRE(13, 1) L1CORE(0)
            L1PRE(14, 0) L1CORE(1)
            L1PRE(15, 1) L1CORE(0)
            L1CORE(1)
        }
#undef L1PRE
#undef L1CORE

        if (unitlane) fcb[eIw][ju] = hj * wfc;
        __syncthreads();
        if (l20 == 0 && e < 4096) {
            float p = bfc[0];
            #pragma unroll
            for (int k = 0; k < 10; ++k) p += fcb[eIw][k];
            out[e] = p;
        }
        if (unitlane && e < 4096) {
            out[4096 + 40960  + e * 10 + ju] = hj;   // h1_T
            out[4096 + 122880 + e * 10 + ju] = cc;   // c1_T
        }
    }
}

extern "C" void kernel_launch(void* const* d_in, const int* in_sizes, int n_in,
                              void* d_out, int out_size, void* d_ws, size_t ws_size,
                              hipStream_t stream) {
    const float* x    = (const float*)d_in[0];
    const float* hid  = (const float*)d_in[1];
    const float* cel  = (const float*)d_in[2];
    const float* Wih0 = (const float*)d_in[3];
    const float* Whh0 = (const float*)d_in[4];
    const float* bih0 = (const float*)d_in[5];
    const float* bhh0 = (const float*)d_in[6];
    const float* Wih1 = (const float*)d_in[7];
    const float* Whh1 = (const float*)d_in[8];
    const float* bih1 = (const float*)d_in[9];
    const float* bhh1 = (const float*)d_in[10];
    const float* Wfc  = (const float*)d_in[11];
    const float* bfc  = (const float*)d_in[12];

    // 683 blocks x 6 elements = 4098 slots (2 padded, store-masked)
    hipLaunchKernelGGL(lstm2_r10, dim3(683), dim3(256), 0, stream,
                       x, hid, cel, Wih0, Whh0, bih0, bhh0,
                       Wih1, Whh1, bih1, bhh1, Wfc, bfc,
                       (float*)d_out);
}